// Round 10
// baseline (336.625 us; speedup 1.0000x reference)
//
#include <hip/hip_runtime.h>

#define LN 8192           // 8194 - 2
#define B_ROWS 4096
#define NMEANS 6

#define COLS_PER_BLOCK 1024   // 256 threads * 4 floats
#define ROWS_PER_BLOCK 64
#define COL_SEGS (LN / COLS_PER_BLOCK)        // 8
#define ROW_CHUNKS (B_ROWS / ROWS_PER_BLOCK)  // 64

typedef float v4f __attribute__((ext_vector_type(4)));

// ---------------------------------------------------------------------------
// Kernel A (CONTROL — identical to R8 best, 26.0 us): correct output.
// ---------------------------------------------------------------------------
__global__ void __launch_bounds__(256)
fused_kernel(const float* __restrict__ w, float* __restrict__ out) {
    const int bid     = blockIdx.x;
    const int colSeg  = bid & (COL_SEGS - 1);        // 0..7
    const int rowBase = (bid >> 3) * ROWS_PER_BLOCK; // 0..4032 step 64

    const int j0 = colSeg * COLS_PER_BLOCK + threadIdx.x * 4;

    const float bk[NMEANS] = {1.99471140f, 1.20985428f, 0.26995483f,
                              0.02215925f, 6.69151e-4f, 7.43360e-6f};
    float a[NMEANS];
#pragma unroll
    for (int k = 0; k < NMEANS; ++k) a[k] = w[k] * bk[k];

    v4f v;
#pragma unroll
    for (int e = 0; e < 4; ++e) {
        float u = (float)(j0 + e) * (5.0f / (float)LN);
        float g = __expf(-0.5f * u * u);
        float E = __expf(u);
        float h = a[5];
        h = h * E + a[4];
        h = h * E + a[3];
        h = h * E + a[2];
        h = h * E + a[1];
        h = h * E + a[0];
        v[e] = g * h;
    }

    float* base = out + (long long)rowBase * LN + j0;
#pragma unroll
    for (int r = 0; r < ROWS_PER_BLOCK; ++r) {
        *(v4f*)(base + (long long)r * LN) = v;
    }
}

// ---------------------------------------------------------------------------
// DIAGNOSTIC: exact fill-clone — grid-stride linear v4f constant stores.
// Launched 3x with grids {256, 1024, 2048} on the same 512 MB of d_ws.
// Distinguish dispatches by Start_Timestamp order / OccupancyPercent
// (256 blocks -> ~3% occ, 1024 -> ~17%, 2048 -> ~33%+).
// ---------------------------------------------------------------------------
__global__ void __launch_bounds__(256)
probe_fill_gs(float* __restrict__ ws, long long n4) {
    const long long stride = (long long)gridDim.x * blockDim.x;
    const v4f v = {1.0f, 1.0f, 1.0f, 1.0f};
    for (long long i = (long long)blockIdx.x * blockDim.x + threadIdx.x;
         i < n4; i += stride) {
        ((v4f*)ws)[i] = v;
    }
}

extern "C" void kernel_launch(void* const* d_in, const int* in_sizes, int n_in,
                              void* d_out, int out_size, void* d_ws, size_t ws_size,
                              hipStream_t stream) {
    const float* w = (const float*)d_in[0];   // weights [6]
    float* out = (float*)d_out;

    // A: correct output (control, identical to R8)
    fused_kernel<<<dim3(COL_SEGS * ROW_CHUNKS), dim3(256), 0, stream>>>(w, out);

    // Grid-size sweep of the fill-clone on up to 512 MB of workspace
    size_t cap = ws_size < (size_t)536870912 ? ws_size : (size_t)536870912;
    long long n4 = (long long)(cap / 16);     // v4f count
    if (n4 > 0) {
        probe_fill_gs<<<dim3(256),  dim3(256), 0, stream>>>((float*)d_ws, n4);
        probe_fill_gs<<<dim3(1024), dim3(256), 0, stream>>>((float*)d_ws, n4);
        probe_fill_gs<<<dim3(2048), dim3(256), 0, stream>>>((float*)d_ws, n4);
    }
}

// Round 11
// 271.787 us; speedup vs baseline: 1.2386x; 1.2386x over previous
//
#include <hip/hip_runtime.h>

#define LN 8192           // 8194 - 2
#define B_ROWS 4096
#define NMEANS 6

#define COLS_PER_BLOCK 1024   // 256 threads * 4 floats
#define ROWS_PER_BLOCK 64
#define COL_SEGS (LN / COLS_PER_BLOCK)        // 8
#define ROW_CHUNKS (B_ROWS / ROWS_PER_BLOCK)  // 64

typedef float v4f __attribute__((ext_vector_type(4)));

// ---------------------------------------------------------------------------
// Kernel A (CONTROL — identical to R8 best, 26.0 us): correct output.
// ---------------------------------------------------------------------------
__global__ void __launch_bounds__(256)
fused_kernel(const float* __restrict__ w, float* __restrict__ out) {
    const int bid     = blockIdx.x;
    const int colSeg  = bid & (COL_SEGS - 1);        // 0..7
    const int rowBase = (bid >> 3) * ROWS_PER_BLOCK; // 0..4032 step 64

    const int j0 = colSeg * COLS_PER_BLOCK + threadIdx.x * 4;

    const float bk[NMEANS] = {1.99471140f, 1.20985428f, 0.26995483f,
                              0.02215925f, 6.69151e-4f, 7.43360e-6f};
    float a[NMEANS];
#pragma unroll
    for (int k = 0; k < NMEANS; ++k) a[k] = w[k] * bk[k];

    v4f v;
#pragma unroll
    for (int e = 0; e < 4; ++e) {
        float u = (float)(j0 + e) * (5.0f / (float)LN);
        float g = __expf(-0.5f * u * u);
        float E = __expf(u);
        float h = a[5];
        h = h * E + a[4];
        h = h * E + a[3];
        h = h * E + a[2];
        h = h * E + a[1];
        h = h * E + a[0];
        v[e] = g * h;
    }

    float* base = out + (long long)rowBase * LN + j0;
#pragma unroll
    for (int r = 0; r < ROWS_PER_BLOCK; ++r) {
        *(v4f*)(base + (long long)r * LN) = v;
    }
}

// ---------------------------------------------------------------------------
// P1: plain dword stores (4 B/lane), 256 WGs, grid-stride. 512 MB.
// ---------------------------------------------------------------------------
__global__ void __launch_bounds__(256)
probe_dword(float* __restrict__ ws, long long n) {
    const long long stride = (long long)gridDim.x * blockDim.x;
    for (long long i = (long long)blockIdx.x * blockDim.x + threadIdx.x;
         i < n; i += stride) {
        ws[i] = 1.0f;
    }
}

// ---------------------------------------------------------------------------
// P2: nontemporal dwordx4 stores (nt=1), 256 WGs, grid-stride. 512 MB.
// (nt lost at 134 MB / MALL-resident scale; retest at MALL-overflow scale.)
// ---------------------------------------------------------------------------
__global__ void __launch_bounds__(256)
probe_nt_x4(float* __restrict__ ws, long long n4) {
    const long long stride = (long long)gridDim.x * blockDim.x;
    const v4f v = {1.0f, 1.0f, 1.0f, 1.0f};
    for (long long i = (long long)blockIdx.x * blockDim.x + threadIdx.x;
         i < n4; i += stride) {
        __builtin_nontemporal_store(v, (v4f*)ws + i);
    }
}

// ---------------------------------------------------------------------------
// P3: dwordx4 stores with sc0 sc1 cache-policy bits (scope/write-through),
// 256 WGs, grid-stride. 512 MB.
// ---------------------------------------------------------------------------
__global__ void __launch_bounds__(256)
probe_sc01_x4(float* __restrict__ ws, long long n4) {
    const long long stride = (long long)gridDim.x * blockDim.x;
    const v4f v = {1.0f, 1.0f, 1.0f, 1.0f};
    for (long long i = (long long)blockIdx.x * blockDim.x + threadIdx.x;
         i < n4; i += stride) {
        v4f* p = (v4f*)ws + i;
        asm volatile("global_store_dwordx4 %0, %1, off sc0 sc1"
                     :: "v"(p), "v"(v) : "memory");
    }
}

extern "C" void kernel_launch(void* const* d_in, const int* in_sizes, int n_in,
                              void* d_out, int out_size, void* d_ws, size_t ws_size,
                              hipStream_t stream) {
    const float* w = (const float*)d_in[0];   // weights [6]
    float* out = (float*)d_out;

    // A: correct output (control, identical to R8)
    fused_kernel<<<dim3(COL_SEGS * ROW_CHUNKS), dim3(256), 0, stream>>>(w, out);

    // Store-flavor sweep on up to 512 MB of workspace, fill-matched 256 WGs
    size_t cap = ws_size < (size_t)536870912 ? ws_size : (size_t)536870912;
    long long n  = (long long)(cap / 4);      // floats
    long long n4 = (long long)(cap / 16);     // v4f
    if (n4 > 0) {
        probe_dword  <<<dim3(256), dim3(256), 0, stream>>>((float*)d_ws, n);
        probe_nt_x4  <<<dim3(256), dim3(256), 0, stream>>>((float*)d_ws, n4);
        probe_sc01_x4<<<dim3(256), dim3(256), 0, stream>>>((float*)d_ws, n4);
    }
}

// Round 12
// 26.782 us; speedup vs baseline: 12.5691x; 10.1482x over previous
//
#include <hip/hip_runtime.h>

#define LN 8192           // 8194 - 2
#define B_ROWS 4096
#define NMEANS 6

#define NBLOCKS 256
#define NTHREADS 256
// One sweep = whole grid's v4f = 256*256*4 floats = 1 MiB = exactly 32 rows.
// 1 MiB % 32 KB row == 0 -> each thread's column is invariant across sweeps:
// compute the row value once, store it 128 times at 1 MiB stride.
#define SWEEP_FLOATS (NBLOCKS * NTHREADS * 4)          // 262,144
#define NSWEEPS ((B_ROWS * LN) / SWEEP_FLOATS)         // 128

typedef float v4f __attribute__((ext_vector_type(4)));

// ---------------------------------------------------------------------------
// R11 store-flavor sweep result (512 MB, 256 WGs, linear):
//   plain dwordx4 4.5 TB/s | plain dword 5.8 | nt dwordx4 7.0 | sc0sc1 7.0
// Plain stores allocate dirty L2 lines (2 memory-side ops/line); nt bypasses
// allocation and streams at the rocclr-fill rate. This kernel is P2's exact
// winning recipe (nt + linear grid-stride + 256 WGs) applied to the output.
//
// row[j] = exp(-0.5u^2) * Horner_k( w_k*norm*e^(-0.5k^2), E=e^u ), u = 5j/8192
// ---------------------------------------------------------------------------
__global__ void __launch_bounds__(256)
fused_nt_kernel(const float* __restrict__ w, float* __restrict__ out) {
    const int tid = blockIdx.x * NTHREADS + threadIdx.x;  // 0..65535
    const int j0  = (tid * 4) & (LN - 1);                 // column, sweep-invariant

    // norm * exp(-0.5*k^2), k = 0..5  (norm = 1/(0.2*sqrt(2*pi)))
    const float bk[NMEANS] = {1.99471140f, 1.20985428f, 0.26995483f,
                              0.02215925f, 6.69151e-4f, 7.43360e-6f};
    float a[NMEANS];
#pragma unroll
    for (int k = 0; k < NMEANS; ++k) a[k] = w[k] * bk[k];

    v4f v;
#pragma unroll
    for (int e = 0; e < 4; ++e) {
        float u = (float)(j0 + e) * (5.0f / (float)LN);   // 5 * pos
        float g = __expf(-0.5f * u * u);
        float E = __expf(u);
        float h = a[5];
        h = h * E + a[4];
        h = h * E + a[3];
        h = h * E + a[2];
        h = h * E + a[1];
        h = h * E + a[0];
        v[e] = g * h;
    }

    // 128 linear sweeps of nontemporal stores: whole grid writes one
    // contiguous 1 MiB window per sweep, streaming at the fill rate.
    float* base = out + (long long)tid * 4;
#pragma unroll 8
    for (int s = 0; s < NSWEEPS; ++s) {
        __builtin_nontemporal_store(v, (v4f*)(base + (long long)s * SWEEP_FLOATS));
    }
}

extern "C" void kernel_launch(void* const* d_in, const int* in_sizes, int n_in,
                              void* d_out, int out_size, void* d_ws, size_t ws_size,
                              hipStream_t stream) {
    const float* w = (const float*)d_in[0];   // weights [6]
    // d_in[1] (inp) is shape-only in the reference -> never read.
    float* out = (float*)d_out;

    fused_nt_kernel<<<dim3(NBLOCKS), dim3(NTHREADS), 0, stream>>>(w, out);
}